// Round 4
// baseline (97.582 us; speedup 1.0000x reference)
//
#include <hip/hip_runtime.h>
#include <hip/hip_bf16.h>
#include <cstdint>

// Problem dims (fixed by reference)
#define G_ 256
#define P_ 1024
#define D_ 128
#define K_ 16
#define H_ 32
#define N_ (G_ * P_)

// d_out layout (floats), in reference return order
constexpr size_t OFF_COARSE = 0;                               // [G*K, D] = 524288
constexpr size_t OFF_ASSIGN = (size_t)G_ * K_ * D_;            // 524288
constexpr size_t OFF_SEND   = OFF_ASSIGN + (size_t)N_ * K_;    // 4718592
constexpr size_t OFF_RECV   = OFF_SEND + (size_t)G_ * K_ * K_; // 4784128
constexpr size_t OFF_EDGE   = OFF_RECV + (size_t)G_ * K_ * K_; // 4849664

// ---------------------------------------------------------------------------
// Kernel 1 (v2): per-node MLP + softmax, M=4 nodes per thread.
// R3 was LDS-issue-bound: 1 node/thread => 1024 ds_read_b128 per wave for W1
// with only 4 FMA per read (~79 us of LDS issue). M=4 reuses each W1 read for
// 4 nodes (16 FMA/read), cutting LDS instructions 4x. x is prefetched one
// d-quad ahead in registers (1 wave/SIMD: global latency must hide in-wave).
// All h/g accumulators: named arrays + fully unrolled loops (static indices).
// ---------------------------------------------------------------------------
#define L1_FMA(hm, am)                                                        \
    hm[4 * jq + 0] = fmaf(am, w.x, hm[4 * jq + 0]);                           \
    hm[4 * jq + 1] = fmaf(am, w.y, hm[4 * jq + 1]);                           \
    hm[4 * jq + 2] = fmaf(am, w.z, hm[4 * jq + 2]);                           \
    hm[4 * jq + 3] = fmaf(am, w.w, hm[4 * jq + 3])

#define L2_FMA(gm, tm)                                                        \
    gm[4 * kq + 0] = fmaf(tm, w.x, gm[4 * kq + 0]);                           \
    gm[4 * kq + 1] = fmaf(tm, w.y, gm[4 * kq + 1]);                           \
    gm[4 * kq + 2] = fmaf(tm, w.z, gm[4 * kq + 2]);                           \
    gm[4 * kq + 3] = fmaf(tm, w.w, gm[4 * kq + 3])

#define SOFTMAX_STORE(gm, node)                                               \
    {                                                                         \
        float mx = gm[0];                                                     \
        _Pragma("unroll")                                                     \
        for (int k = 1; k < K_; ++k) mx = fmaxf(mx, gm[k]);                   \
        float e[K_];                                                          \
        float sum = 0.f;                                                      \
        _Pragma("unroll")                                                     \
        for (int k = 0; k < K_; ++k) { e[k] = __expf(gm[k] - mx); sum += e[k]; } \
        const float inv = 1.0f / sum;                                         \
        float4* __restrict__ ar = (float4*)(assign_out + (size_t)(node) * K_);\
        _Pragma("unroll")                                                     \
        for (int kq = 0; kq < K_ / 4; ++kq)                                   \
            ar[kq] = make_float4(e[4 * kq + 0] * inv, e[4 * kq + 1] * inv,    \
                                 e[4 * kq + 2] * inv, e[4 * kq + 3] * inv);   \
    }

__global__ __launch_bounds__(256) void mlp_assign_kernel(
    const float* __restrict__ x, const float* __restrict__ W1,
    const float* __restrict__ b1, const float* __restrict__ W2,
    const float* __restrict__ b2, float* __restrict__ assign_out)
{
    __shared__ float W1s[D_ * H_];   // 16 KB, [d][j]
    __shared__ float W2s[H_ * K_];   // 2 KB,  [j][k]
    __shared__ float b1s[H_];
    __shared__ float b2s[K_];

    const int tid = threadIdx.x;
    for (int i = tid; i < D_ * H_; i += 256) W1s[i] = W1[i];
    for (int i = tid; i < H_ * K_; i += 256) W2s[i] = W2[i];
    if (tid < H_) b1s[tid] = b1[tid];
    if (tid < K_) b2s[tid] = b2[tid];
    __syncthreads();

    const size_t n0 = (size_t)blockIdx.x * 1024 + tid;  // nodes n0 + m*256
    const float4* __restrict__ xr0 = (const float4*)(x + n0 * D_);
    const float4* __restrict__ xr1 = (const float4*)(x + (n0 + 256) * D_);
    const float4* __restrict__ xr2 = (const float4*)(x + (n0 + 512) * D_);
    const float4* __restrict__ xr3 = (const float4*)(x + (n0 + 768) * D_);
    const float4* __restrict__ W1v = (const float4*)W1s;
    const float4* __restrict__ W2v = (const float4*)W2s;

    float h0[H_], h1[H_], h2[H_], h3[H_];
#pragma unroll
    for (int j = 0; j < H_; ++j) {
        const float bj = b1s[j];
        h0[j] = bj; h1[j] = bj; h2[j] = bj; h3[j] = bj;
    }

    // layer 1: 32 iters x 4 d each; prefetch next d-quad while computing
    float4 c0 = xr0[0], c1 = xr1[0], c2 = xr2[0], c3 = xr3[0];
#pragma unroll 1
    for (int i = 0; i < 32; ++i) {
        float4 p0, p1, p2, p3;
        if (i < 31) { p0 = xr0[i + 1]; p1 = xr1[i + 1]; p2 = xr2[i + 1]; p3 = xr3[i + 1]; }
        const float a0[4] = {c0.x, c0.y, c0.z, c0.w};
        const float a1[4] = {c1.x, c1.y, c1.z, c1.w};
        const float a2[4] = {c2.x, c2.y, c2.z, c2.w};
        const float a3[4] = {c3.x, c3.y, c3.z, c3.w};
#pragma unroll
        for (int dd = 0; dd < 4; ++dd) {
            const int d = 4 * i + dd;
#pragma unroll
            for (int jq = 0; jq < H_ / 4; ++jq) {
                const float4 w = W1v[d * (H_ / 4) + jq];  // broadcast b128
                L1_FMA(h0, a0[dd]);
                L1_FMA(h1, a1[dd]);
                L1_FMA(h2, a2[dd]);
                L1_FMA(h3, a3[dd]);
            }
        }
        c0 = p0; c1 = p1; c2 = p2; c3 = p3;
    }

    // layer 2 (relu fused), W2 row shared across the 4 nodes
    float g0[K_], g1[K_], g2[K_], g3[K_];
#pragma unroll
    for (int k = 0; k < K_; ++k) {
        const float bk = b2s[k];
        g0[k] = bk; g1[k] = bk; g2[k] = bk; g3[k] = bk;
    }
#pragma unroll
    for (int j = 0; j < H_; ++j) {
        const float t0 = fmaxf(h0[j], 0.f);
        const float t1 = fmaxf(h1[j], 0.f);
        const float t2 = fmaxf(h2[j], 0.f);
        const float t3 = fmaxf(h3[j], 0.f);
#pragma unroll
        for (int kq = 0; kq < K_ / 4; ++kq) {
            const float4 w = W2v[j * (K_ / 4) + kq];
            L2_FMA(g0, t0);
            L2_FMA(g1, t1);
            L2_FMA(g2, t2);
            L2_FMA(g3, t3);
        }
    }

    SOFTMAX_STORE(g0, n0);
    SOFTMAX_STORE(g1, n0 + 256);
    SOFTMAX_STORE(g2, n0 + 512);
    SOFTMAX_STORE(g3, n0 + 768);
}

// ---------------------------------------------------------------------------
// Kernel 2 (v3): coarse[g][k][d] = sum_{n in g} assign[n][k] * x[n][d]
// One block per graph, 1024 threads, 32-node LDS chunks, double-buffered
// reg->LDS staging. Thread = (dq, s); each thread owns all 16 k's:
// 5 ds_read_b128 + 64 FMA per chunk. acc float4[16], all static indices.
// ---------------------------------------------------------------------------
#define FMA4(dst, v, sc)                                                      \
    dst.x = fmaf(v.x, sc, dst.x); dst.y = fmaf(v.y, sc, dst.y);               \
    dst.z = fmaf(v.z, sc, dst.z); dst.w = fmaf(v.w, sc, dst.w)

__global__ __launch_bounds__(1024, 4) void coarse_kernel(
    const float* __restrict__ x, const float* __restrict__ assign,
    const int* __restrict__ n_node, float* __restrict__ coarse)
{
    __shared__ float xs[2][32 * 128];   // 2 x 16 KB node-feature chunks
    __shared__ float as_[2][32 * 16];   // 2 x 2 KB assignment chunks
    __shared__ int pref[G_];

    const int tid = threadIdx.x;

    if (tid < G_) pref[tid] = n_node[tid];
    __syncthreads();
    for (int st = 1; st < G_; st <<= 1) {
        int v = 0;
        if (tid < G_ && tid >= st) v = pref[tid - st];
        __syncthreads();
        if (tid < G_ && tid >= st) pref[tid] += v;
        __syncthreads();
    }
    const int g = blockIdx.x;
    const int start = (g == 0) ? 0 : min(pref[g - 1], N_);
    const int end   = (g == G_ - 1) ? N_ : min(pref[g], N_);

    const int dq = tid & 31;   // d = 4*dq .. 4*dq+3
    const int s  = tid >> 5;   // node slot within chunk, 0..31

    float4 acc[K_];
#pragma unroll
    for (int k = 0; k < K_; ++k) acc[k] = make_float4(0.f, 0.f, 0.f, 0.f);

    const int total = end - start;
    const int nfull = total >> 5;
    const int tail  = total & 31;

    float4 rx = make_float4(0.f, 0.f, 0.f, 0.f);
    float4 ra = make_float4(0.f, 0.f, 0.f, 0.f);
    if (nfull > 0) {
        rx = *(const float4*)(x + (size_t)start * D_ + tid * 4);
        if (tid < 128)
            ra = *(const float4*)(assign + (size_t)start * K_ + tid * 4);
    }

    int b = 0;
    for (int c = 0; c < nfull; ++c) {
        *(float4*)(&xs[b][tid * 4]) = rx;
        if (tid < 128) *(float4*)(&as_[b][tid * 4]) = ra;
        __syncthreads();

        if (c + 1 < nfull) {
            const size_t nb = (size_t)start + (size_t)(c + 1) * 32;
            rx = *(const float4*)(x + nb * D_ + tid * 4);
            if (tid < 128)
                ra = *(const float4*)(assign + nb * K_ + tid * 4);
        }

        const float4 xv = *(const float4*)(&xs[b][s * D_ + dq * 4]);
        const float4* av = (const float4*)(&as_[b][s * K_]);
#pragma unroll
        for (int q = 0; q < 4; ++q) {
            const float4 a = av[q];
            FMA4(acc[4 * q + 0], xv, a.x);
            FMA4(acc[4 * q + 1], xv, a.y);
            FMA4(acc[4 * q + 2], xv, a.z);
            FMA4(acc[4 * q + 3], xv, a.w);
        }
        b ^= 1;
    }

    if (tail > 0 && s < tail) {
        const size_t n = (size_t)start + (size_t)nfull * 32 + s;
        const float4 xv = *(const float4*)(x + n * D_ + dq * 4);
        const float4* av = (const float4*)(assign + n * K_);
#pragma unroll
        for (int q = 0; q < 4; ++q) {
            const float4 a = av[q];
            FMA4(acc[4 * q + 0], xv, a.x);
            FMA4(acc[4 * q + 1], xv, a.y);
            FMA4(acc[4 * q + 2], xv, a.z);
            FMA4(acc[4 * q + 3], xv, a.w);
        }
    }

    // exact reduction over the 32 node-slots, fully unrolled (static acc idx)
    __syncthreads();
    float* red = &xs[0][0];
#pragma unroll
    for (int k = 0; k < K_; ++k) {
        *(float4*)(&red[s * D_ + dq * 4]) = acc[k];
        __syncthreads();
        if (tid < D_) {
            float sum = 0.f;
#pragma unroll
            for (int ss = 0; ss < 32; ++ss) sum += red[ss * D_ + tid];
            coarse[((size_t)g * K_ + k) * D_ + tid] = sum;
        }
        __syncthreads();
    }
}

// ---------------------------------------------------------------------------
// Kernel 3: fully-connected coarse edges per graph
// ---------------------------------------------------------------------------
__global__ __launch_bounds__(256) void edges_kernel(float* __restrict__ out)
{
    const int e = blockIdx.x * 256 + threadIdx.x;  // 0 .. G*K*K-1
    const int g = e >> 8;
    const int pair = e & 255;
    const int i = pair >> 4;
    const int j = pair & 15;
    out[OFF_SEND + e] = (float)(g * K_ + i);
    out[OFF_RECV + e] = (float)(g * K_ + j);
    out[OFF_EDGE + e] = 1.0f;
}

extern "C" void kernel_launch(void* const* d_in, const int* in_sizes, int n_in,
                              void* d_out, int out_size, void* d_ws, size_t ws_size,
                              hipStream_t stream)
{
    const float* x      = (const float*)d_in[0];
    const float* W1     = (const float*)d_in[1];
    const float* b1     = (const float*)d_in[2];
    const float* W2     = (const float*)d_in[3];
    const float* b2     = (const float*)d_in[4];
    const int*   n_node = (const int*)d_in[5];
    float* out = (float*)d_out;

    mlp_assign_kernel<<<N_ / 1024, 256, 0, stream>>>(x, W1, b1, W2, b2, out + OFF_ASSIGN);
    coarse_kernel<<<G_, 1024, 0, stream>>>(x, out + OFF_ASSIGN, n_node, out + OFF_COARSE);
    edges_kernel<<<(G_ * K_ * K_) / 256, 256, 0, stream>>>(out);
}

// Round 5
// 64.336 us; speedup vs baseline: 1.5167x; 1.5167x over previous
//
#include <hip/hip_runtime.h>
#include <hip/hip_bf16.h>
#include <cstdint>

// Problem dims (fixed by reference)
#define G_ 256
#define P_ 1024
#define D_ 128
#define K_ 16
#define H_ 32
#define N_ (G_ * P_)

// d_out layout (floats), in reference return order
constexpr size_t OFF_COARSE = 0;                               // [G*K, D] = 524288
constexpr size_t OFF_ASSIGN = (size_t)G_ * K_ * D_;            // 524288
constexpr size_t OFF_SEND   = OFF_ASSIGN + (size_t)N_ * K_;    // 4718592
constexpr size_t OFF_RECV   = OFF_SEND + (size_t)G_ * K_ * K_; // 4784128
constexpr size_t OFF_EDGE   = OFF_RECV + (size_t)G_ * K_ * K_; // 4849664

typedef __attribute__((ext_vector_type(8))) short bf16x8;   // 8 bf16 (4 VGPR)
typedef __attribute__((ext_vector_type(4))) float f32x4;    // MFMA C/D

// Exact-ish split: x ~= hi + lo with hi,lo bf16 (truncation; residual captures
// the rest). Product error ~2^-16 relative -> near-f32 GEMM via 3 MFMA passes.
__device__ __forceinline__ void splitf(float x, short& h, short& l) {
    const unsigned u = __float_as_uint(x);
    h = (short)(u >> 16);
    const float hf = __uint_as_float(u & 0xffff0000u);
    const float r = x - hf;
    l = (short)(__float_as_uint(r) >> 16);
}

// ---------------------------------------------------------------------------
// Kernel 1 (v3, MFMA): per-node MLP + softmax.
// R4 lesson: the VALU+LDS-broadcast scheme has a structural floor (18KB of
// LDS-delivered W bytes per node / M, and TLP falls as M rises). MFMA shares
// W across lanes in hardware. Wave = 64 nodes; W1/W2 frags in registers
// (built once, 72 L2 scalar loads); x A-frags direct from global; split-bf16
// (hi+lo) x3 MFMA for ~f32 accuracy. h re-fragments via wave-private LDS.
// Fragment maps (16x16x32): A row=lane&15, k=(lane>>4)*8+e; B col=lane&15,
// same k; C/D col=lane&15, row=(lane>>4)*4+reg [verified m89/m91].
// ---------------------------------------------------------------------------
__global__ __launch_bounds__(256, 2) void mlp_assign_mfma(
    const float* __restrict__ x, const float* __restrict__ W1,
    const float* __restrict__ b1, const float* __restrict__ W2,
    const float* __restrict__ b2, float* __restrict__ assign_out)
{
    __shared__ float hlds[4][64 * 36];  // per-wave h scratch, pitch 36 floats

    const int tid  = threadIdx.x;
    const int lane = tid & 63;
    const int wave = tid >> 6;
    const int q = lane >> 4;   // 0..3 (k-block / row-group selector)
    const int c = lane & 15;   // 0..15 (row for A, col for B/D)

    // ---- W1 fragments (hi/lo), kb = K-step, nt = 16-wide n-tile of H ----
    bf16x8 w1h[4][2], w1l[4][2];
#pragma unroll
    for (int kb = 0; kb < 4; ++kb)
#pragma unroll
        for (int nt = 0; nt < 2; ++nt)
#pragma unroll
            for (int e = 0; e < 8; ++e) {
                const int k = kb * 32 + q * 8 + e;
                short hb, lb; splitf(W1[k * H_ + nt * 16 + c], hb, lb);
                w1h[kb][nt][e] = hb; w1l[kb][nt][e] = lb;
            }
    // ---- W2 fragment: k = j = q*8+e (H=32), n = c (K=16) ----
    bf16x8 w2h, w2l;
#pragma unroll
    for (int e = 0; e < 8; ++e) {
        short hb, lb; splitf(W2[(q * 8 + e) * K_ + c], hb, lb);
        w2h[e] = hb; w2l[e] = lb;
    }
    const float b1v0 = b1[c];
    const float b1v1 = b1[16 + c];
    const float b2v  = b2[c];

    const size_t base = (size_t)blockIdx.x * 256 + (size_t)wave * 64;

    // ---- layer 1: h[64,32] = x[64,128] @ W1 + b1 ----
    f32x4 acc[4][2];
#pragma unroll
    for (int mt = 0; mt < 4; ++mt) {
        acc[mt][0] = f32x4{b1v0, b1v0, b1v0, b1v0};
        acc[mt][1] = f32x4{b1v1, b1v1, b1v1, b1v1};
    }
#pragma unroll
    for (int kb = 0; kb < 4; ++kb) {
        bf16x8 ah[4], al[4];
#pragma unroll
        for (int mt = 0; mt < 4; ++mt) {
            const float* rp = x + (base + mt * 16 + c) * D_ + kb * 32 + q * 8;
            const float4 v0 = *(const float4*)rp;
            const float4 v1 = *(const float4*)(rp + 4);
            const float vv[8] = {v0.x, v0.y, v0.z, v0.w, v1.x, v1.y, v1.z, v1.w};
#pragma unroll
            for (int e = 0; e < 8; ++e) {
                short hb, lb; splitf(vv[e], hb, lb);
                ah[mt][e] = hb; al[mt][e] = lb;
            }
        }
#pragma unroll
        for (int mt = 0; mt < 4; ++mt)
#pragma unroll
            for (int nt = 0; nt < 2; ++nt) {
                acc[mt][nt] = __builtin_amdgcn_mfma_f32_16x16x32_bf16(ah[mt], w1h[kb][nt], acc[mt][nt], 0, 0, 0);
                acc[mt][nt] = __builtin_amdgcn_mfma_f32_16x16x32_bf16(ah[mt], w1l[kb][nt], acc[mt][nt], 0, 0, 0);
                acc[mt][nt] = __builtin_amdgcn_mfma_f32_16x16x32_bf16(al[mt], w1h[kb][nt], acc[mt][nt], 0, 0, 0);
            }
    }

    // relu + park h in wave-private LDS (row = mt*16+q*4+reg, col = nt*16+c);
    // same-wave RAW through the same pointer -> compiler inserts lgkmcnt.
    float* hl = &hlds[wave][0];
#pragma unroll
    for (int mt = 0; mt < 4; ++mt)
#pragma unroll
        for (int nt = 0; nt < 2; ++nt)
#pragma unroll
            for (int r = 0; r < 4; ++r)
                hl[(mt * 16 + q * 4 + r) * 36 + nt * 16 + c] = fmaxf(acc[mt][nt][r], 0.f);

    // ---- layer 2: logits[64,16] = relu(h)[64,32] @ W2 + b2 ----
    f32x4 lacc[4];
#pragma unroll
    for (int mt = 0; mt < 4; ++mt) lacc[mt] = f32x4{b2v, b2v, b2v, b2v};
#pragma unroll
    for (int mt = 0; mt < 4; ++mt) {
        const float* rp = hl + (mt * 16 + c) * 36 + q * 8;
        const float4 v0 = *(const float4*)rp;
        const float4 v1 = *(const float4*)(rp + 4);
        const float vv[8] = {v0.x, v0.y, v0.z, v0.w, v1.x, v1.y, v1.z, v1.w};
        bf16x8 ah, al;
#pragma unroll
        for (int e = 0; e < 8; ++e) {
            short hb, lb; splitf(vv[e], hb, lb);
            ah[e] = hb; al[e] = lb;
        }
        lacc[mt] = __builtin_amdgcn_mfma_f32_16x16x32_bf16(ah, w2h, lacc[mt], 0, 0, 0);
        lacc[mt] = __builtin_amdgcn_mfma_f32_16x16x32_bf16(ah, w2l, lacc[mt], 0, 0, 0);
        lacc[mt] = __builtin_amdgcn_mfma_f32_16x16x32_bf16(al, w2h, lacc[mt], 0, 0, 0);
    }

    // ---- softmax over K=16: each row's 16 logits live in the 16 lanes of a
    // q-group (col = c), at reg r -> reduce with 16-wide shfl_xor ----
#pragma unroll
    for (int mt = 0; mt < 4; ++mt)
#pragma unroll
        for (int r = 0; r < 4; ++r) {
            const float v = lacc[mt][r];
            float mx = v;
#pragma unroll
            for (int s = 1; s < 16; s <<= 1) mx = fmaxf(mx, __shfl_xor(mx, s, 16));
            const float e = __expf(v - mx);
            float sum = e;
#pragma unroll
            for (int s = 1; s < 16; s <<= 1) sum += __shfl_xor(sum, s, 16);
            assign_out[(base + mt * 16 + q * 4 + r) * K_ + c] = e / sum;
        }
}

// ---------------------------------------------------------------------------
// Kernel 2 (v3, unchanged from R3 — ~5 us): coarse segment-sum
// ---------------------------------------------------------------------------
#define FMA4(dst, v, sc)                                                      \
    dst.x = fmaf(v.x, sc, dst.x); dst.y = fmaf(v.y, sc, dst.y);               \
    dst.z = fmaf(v.z, sc, dst.z); dst.w = fmaf(v.w, sc, dst.w)

__global__ __launch_bounds__(1024, 4) void coarse_kernel(
    const float* __restrict__ x, const float* __restrict__ assign,
    const int* __restrict__ n_node, float* __restrict__ coarse)
{
    __shared__ float xs[2][32 * 128];
    __shared__ float as_[2][32 * 16];
    __shared__ int pref[G_];

    const int tid = threadIdx.x;

    if (tid < G_) pref[tid] = n_node[tid];
    __syncthreads();
    for (int st = 1; st < G_; st <<= 1) {
        int v = 0;
        if (tid < G_ && tid >= st) v = pref[tid - st];
        __syncthreads();
        if (tid < G_ && tid >= st) pref[tid] += v;
        __syncthreads();
    }
    const int g = blockIdx.x;
    const int start = (g == 0) ? 0 : min(pref[g - 1], N_);
    const int end   = (g == G_ - 1) ? N_ : min(pref[g], N_);

    const int dq = tid & 31;
    const int s  = tid >> 5;

    float4 acc[K_];
#pragma unroll
    for (int k = 0; k < K_; ++k) acc[k] = make_float4(0.f, 0.f, 0.f, 0.f);

    const int total = end - start;
    const int nfull = total >> 5;
    const int tail  = total & 31;

    float4 rx = make_float4(0.f, 0.f, 0.f, 0.f);
    float4 ra = make_float4(0.f, 0.f, 0.f, 0.f);
    if (nfull > 0) {
        rx = *(const float4*)(x + (size_t)start * D_ + tid * 4);
        if (tid < 128)
            ra = *(const float4*)(assign + (size_t)start * K_ + tid * 4);
    }

    int b = 0;
    for (int c = 0; c < nfull; ++c) {
        *(float4*)(&xs[b][tid * 4]) = rx;
        if (tid < 128) *(float4*)(&as_[b][tid * 4]) = ra;
        __syncthreads();

        if (c + 1 < nfull) {
            const size_t nb = (size_t)start + (size_t)(c + 1) * 32;
            rx = *(const float4*)(x + nb * D_ + tid * 4);
            if (tid < 128)
                ra = *(const float4*)(assign + nb * K_ + tid * 4);
        }

        const float4 xv = *(const float4*)(&xs[b][s * D_ + dq * 4]);
        const float4* av = (const float4*)(&as_[b][s * K_]);
#pragma unroll
        for (int qq = 0; qq < 4; ++qq) {
            const float4 a = av[qq];
            FMA4(acc[4 * qq + 0], xv, a.x);
            FMA4(acc[4 * qq + 1], xv, a.y);
            FMA4(acc[4 * qq + 2], xv, a.z);
            FMA4(acc[4 * qq + 3], xv, a.w);
        }
        b ^= 1;
    }

    if (tail > 0 && s < tail) {
        const size_t n = (size_t)start + (size_t)nfull * 32 + s;
        const float4 xv = *(const float4*)(x + n * D_ + dq * 4);
        const float4* av = (const float4*)(assign + n * K_);
#pragma unroll
        for (int qq = 0; qq < 4; ++qq) {
            const float4 a = av[qq];
            FMA4(acc[4 * qq + 0], xv, a.x);
            FMA4(acc[4 * qq + 1], xv, a.y);
            FMA4(acc[4 * qq + 2], xv, a.z);
            FMA4(acc[4 * qq + 3], xv, a.w);
        }
    }

    __syncthreads();
    float* red = &xs[0][0];
#pragma unroll
    for (int k = 0; k < K_; ++k) {
        *(float4*)(&red[s * D_ + dq * 4]) = acc[k];
        __syncthreads();
        if (tid < D_) {
            float sum = 0.f;
#pragma unroll
            for (int ss = 0; ss < 32; ++ss) sum += red[ss * D_ + tid];
            coarse[((size_t)g * K_ + k) * D_ + tid] = sum;
        }
        __syncthreads();
    }
}

// ---------------------------------------------------------------------------
// Kernel 3: fully-connected coarse edges per graph
// ---------------------------------------------------------------------------
__global__ __launch_bounds__(256) void edges_kernel(float* __restrict__ out)
{
    const int e = blockIdx.x * 256 + threadIdx.x;
    const int g = e >> 8;
    const int pair = e & 255;
    const int i = pair >> 4;
    const int j = pair & 15;
    out[OFF_SEND + e] = (float)(g * K_ + i);
    out[OFF_RECV + e] = (float)(g * K_ + j);
    out[OFF_EDGE + e] = 1.0f;
}

extern "C" void kernel_launch(void* const* d_in, const int* in_sizes, int n_in,
                              void* d_out, int out_size, void* d_ws, size_t ws_size,
                              hipStream_t stream)
{
    const float* x      = (const float*)d_in[0];
    const float* W1     = (const float*)d_in[1];
    const float* b1     = (const float*)d_in[2];
    const float* W2     = (const float*)d_in[3];
    const float* b2     = (const float*)d_in[4];
    const int*   n_node = (const int*)d_in[5];
    float* out = (float*)d_out;

    mlp_assign_mfma<<<N_ / 256, 256, 0, stream>>>(x, W1, b1, W2, b2, out + OFF_ASSIGN);
    coarse_kernel<<<G_, 1024, 0, stream>>>(x, out + OFF_ASSIGN, n_node, out + OFF_COARSE);
    edges_kernel<<<(G_ * K_ * K_) / 256, 256, 0, stream>>>(out);
}